// Round 5
// baseline (112.756 us; speedup 1.0000x reference)
//
#include <hip/hip_runtime.h>

// Tropical (max-plus) matmul: out[n,m] = max_k(|x[n,k]| + |w[m,k]|)
// N=1024, K=256, M=1024, fp32.
//
// Round 5:
//  - lane <-> m (64 m per wave), 16 n-rows per wave (acc[16]) -> only
//    1 ds_read_b64 of w per k-pair feeds 32 VALU combine insts (LDS ~10% load).
//  - w staged k-pair-major: v2f ws[kp*66 + m]; inner-loop lane stride =
//    2 words -> 2-way bank aliasing only (free). R4's bug was stride ≡ 0 mod 4
//    (8-way conflict on every transpose read).
//  - x is wave-uniform -> scalar loads; combine = v_pk_add_f32 + v_max3_f32.
//  - 64x64 tile per block (4 waves x 16n), split-K=4 -> 1024 blocks
//    = 4 blocks/CU = 4 waves/SIMD. One staging phase, ONE barrier.
//  - k-slices combined via COALESCED int atomicMax (values >= 0 -> IEEE bits
//    monotone; 0x00 memset and 0xAAAAAAAA poison are both < any result).

typedef float v2f __attribute__((ext_vector_type(2)));
typedef float v4f __attribute__((ext_vector_type(4)));

constexpr int K      = 256;
constexpr int M      = 1024;
constexpr int KSL    = 64;            // k per slice (per block)
constexpr int PITCHV = 66;            // v2f per kp row: 64 + 2 pad

__global__ void __launch_bounds__(256, 4)
tropical_kernel(const float* __restrict__ xg, const float* __restrict__ wg,
                float* __restrict__ outg)
{
    __shared__ __align__(16) v2f ws[(KSL / 2) * PITCHV];   // 16,896 B

    const int bid   = blockIdx.x;
    const int slice = bid >> 8;            // 0..3
    const int tile  = bid & 255;           // 16 x 16 tiles of 64x64
    const int bn = (tile >> 4) * 64;
    const int bm = (tile & 15) * 64;
    const int k0 = slice * KSL;

    const int tid  = threadIdx.x;
    const int lane = tid & 63;
    const int wv   = __builtin_amdgcn_readfirstlane(tid >> 6);  // 0..3

    // ---- Stage |w| slice (64 rows x 64 k) into LDS, k-pair-major.
    // Thread: row r = tid>>2 (0..63), 16 consecutive k at kc.
    {
        const int r  = tid >> 2;
        const int kc = (tid & 3) * 16;
        const float* wp = wg + (bm + r) * K + k0 + kc;
#pragma unroll
        for (int i = 0; i < 4; ++i) {
            v4f t = *(const v4f*)(wp + 4 * i);
            const int kp = (kc >> 1) + 2 * i;
            ws[(kp    ) * PITCHV + r] = (v2f){fabsf(t.x), fabsf(t.y)};
            ws[(kp + 1) * PITCHV + r] = (v2f){fabsf(t.z), fabsf(t.w)};
        }
    }
    __syncthreads();

    // ---- Inner loop: 32 k-pairs x 16 n-rows.
    // x rows are wave-uniform -> scalar loads + s_and abs.
    const float* xbase = xg + (bn + 16 * wv) * K + k0;   // wave-uniform

    float acc[16];
#pragma unroll
    for (int j = 0; j < 16; ++j) acc[j] = 0.0f;   // sums >= 0: safe identity

#pragma unroll
    for (int kp = 0; kp < KSL / 2; ++kp) {
        v2f wvp = ws[kp * PITCHV + lane];          // ds_read_b64, 2-way = free
#pragma unroll
        for (int j = 0; j < 16; ++j) {
            const float* xr = xbase + j * K;
            v2f xu = (v2f){fabsf(xr[2 * kp]), fabsf(xr[2 * kp + 1])};  // scalar
            v2f s  = wvp + xu;                          // v_pk_add_f32
            acc[j] = fmaxf(acc[j], fmaxf(s.x, s.y));    // v_max3_f32
        }
    }

    // ---- Combine k-slices: coalesced int atomicMax (lane = m).
    int* op = (int*)outg;
#pragma unroll
    for (int j = 0; j < 16; ++j)
        atomicMax(&op[(bn + 16 * wv + j) * M + bm + lane],
                  __float_as_int(acc[j]));
}

extern "C" void kernel_launch(void* const* d_in, const int* in_sizes, int n_in,
                              void* d_out, int out_size, void* d_ws, size_t ws_size,
                              hipStream_t stream)
{
    const float* x = (const float*)d_in[0];   // [1024, 256]
    const float* w = (const float*)d_in[1];   // [1024, 256]
    float* out = (float*)d_out;               // [1024, 1024]

    dim3 grid(1024);   // 256 tiles x 4 k-slices
    dim3 block(256);
    tropical_kernel<<<grid, block, 0, stream>>>(x, w, out);
}

// Round 6
// 97.333 us; speedup vs baseline: 1.1585x; 1.1585x over previous
//
#include <hip/hip_runtime.h>
#include <stdint.h>

// Tropical (max-plus) matmul: out[n,m] = max_k(|x[n,k]| + |w[m,k]|)
// N=1024, K=256, M=1024, fp32.
//
// Round 6: strip ALL non-VALU structure. No LDS, no barriers, no atomics,
// no split-K.
//  - lane <-> m: each lane owns output column bm+lane and reads its own
//    w row straight from global (L2-resident, 1 KB/row) in 32-k chunks,
//    prefetched one chunk ahead into VGPRs.
//  - x rows are wave-uniform -> scalar loads, HOISTED as 8xv4f locals per
//    (row, chunk) so they batch into wide s_loads with a single wait
//    (R5's killer: 512 tight-dependence s_load_dword waits per slice).
//  - abs(x) via 64-bit mask (s_and_b64) keeps SGPR pairs aligned so
//    v_pk_add_f32 can take the pair as its one scalar operand.
//  - inner loop: v_pk_add_f32 + v_max3_f32, 8 independent acc chains.
//  - 512-thr blocks (8 waves x 8 n-rows), 64x64 tile, 256 blocks
//    = 2 blocks/CU = 2 waves/SIMD; stores fully coalesced, 4 MB exact.

typedef float v2f __attribute__((ext_vector_type(2)));
typedef float v4f __attribute__((ext_vector_type(4)));

constexpr int K  = 256;
constexpr int M  = 1024;
constexpr int KC = 32;              // k per chunk
constexpr int NCH = K / KC;         // 8 chunks

static __device__ inline v2f abs2(double d) {
    uint64_t b = __builtin_bit_cast(uint64_t, d) & 0x7FFFFFFF7FFFFFFFULL;
    return __builtin_bit_cast(v2f, b);
}

__global__ void __launch_bounds__(512)
tropical_kernel(const float* __restrict__ xg, const float* __restrict__ wg,
                float* __restrict__ outg)
{
    const int tid  = threadIdx.x;
    const int lane = tid & 63;
    const int wv   = __builtin_amdgcn_readfirstlane(tid >> 6);  // 0..7

    const int bn = (int)(blockIdx.x >> 4) * 64;
    const int bm = (int)(blockIdx.x & 15) * 64;

    const float* wrow = wg + (bm + lane) * K;   // per-lane w row (uncoalesced
                                                // across lanes, L2-resident)
    const int n0 = bn + 8 * wv;                 // wave's 8 n rows (uniform)
    const float* xrow = xg + n0 * K;            // uniform base

    float acc[8];
#pragma unroll
    for (int j = 0; j < 8; ++j) acc[j] = 0.0f;  // sums >= 0: safe identity

    // Prefetch w chunk 0.
    v4f wf[KC / 4];
#pragma unroll
    for (int q = 0; q < KC / 4; ++q) wf[q] = *(const v4f*)(wrow + 4 * q);

    for (int c = 0; c < NCH; ++c) {
        // |w| chunk in v2f registers.
        v2f wa[KC / 2];
#pragma unroll
        for (int q = 0; q < KC / 4; ++q) {
            v4f t = wf[q];
            wa[2 * q]     = (v2f){fabsf(t.x), fabsf(t.y)};
            wa[2 * q + 1] = (v2f){fabsf(t.z), fabsf(t.w)};
        }
        // Prefetch next w chunk (stays in flight during compute).
        if (c + 1 < NCH) {
#pragma unroll
            for (int q = 0; q < KC / 4; ++q)
                wf[q] = *(const v4f*)(wrow + (c + 1) * KC + 4 * q);
        }

#pragma unroll
        for (int j = 0; j < 8; ++j) {
            const double* xr = (const double*)(xrow + j * K + c * KC);  // uniform
            // Hoisted batch of uniform loads -> wide s_load, one wait.
            double xb[KC / 2];
#pragma unroll
            for (int kp = 0; kp < KC / 2; ++kp) xb[kp] = xr[kp];
#pragma unroll
            for (int kp = 0; kp < KC / 2; ++kp) {
                v2f xu = abs2(xb[kp]);                    // s_and_b64
                v2f s  = wa[kp] + xu;                     // v_pk_add_f32
                acc[j] = fmaxf(acc[j], fmaxf(s.x, s.y));  // v_max3_f32
            }
        }
    }

    // Coalesced stores: lane = m.
#pragma unroll
    for (int j = 0; j < 8; ++j)
        outg[(n0 + j) * M + bm + lane] = acc[j];
}

extern "C" void kernel_launch(void* const* d_in, const int* in_sizes, int n_in,
                              void* d_out, int out_size, void* d_ws, size_t ws_size,
                              hipStream_t stream)
{
    const float* x = (const float*)d_in[0];   // [1024, 256]
    const float* w = (const float*)d_in[1];   // [1024, 256]
    float* out = (float*)d_out;               // [1024, 1024]

    dim3 grid(256);    // 16 x 16 tiles of 64x64
    dim3 block(512);   // 8 waves x 8 n-rows
    tropical_kernel<<<grid, block, 0, stream>>>(x, w, out);
}